// Round 1
// baseline (2077.583 us; speedup 1.0000x reference)
//
#include <hip/hip_runtime.h>
#include <hip/hip_bf16.h>

#define N_NODES 10000
#define N_EDGES 128000
#define C_DIM   128

// ---------------- helpers ----------------

__device__ __forceinline__ float silu_f(float x) {
  return x / (1.f + __expf(-x));
}

__device__ __forceinline__ unsigned short f2bf(float x) {
  __hip_bfloat16 b = __float2bfloat16(x);
  return *(unsigned short*)&b;
}

// ---------------- h = feats @ W_up  [N,128]x[128,128] ----------------
__global__ __launch_bounds__(256) void k_h(const float* __restrict__ feats,
                                           const float* __restrict__ Wup,
                                           float* __restrict__ h) {
  __shared__ float sF[32][129];
  int tid = threadIdx.x;
  int n0 = blockIdx.x * 32;
  int nmax = N_NODES - n0; if (nmax > 32) nmax = 32;
  for (int i = tid; i < 32 * 128; i += 256) {
    int nn = i >> 7, kk = i & 127;
    sF[nn][kk] = (nn < nmax) ? feats[(n0 + nn) * 128 + kk] : 0.f;
  }
  __syncthreads();
  int n = tid >> 3;          // 0..31
  int jb = (tid & 7) * 16;   // 0..112
  if (n < nmax) {
    float4 acc[4] = {};
    for (int k = 0; k < 128; k++) {
      float a = sF[n][k];
      #pragma unroll
      for (int jg = 0; jg < 4; jg++) {
        float4 w = *(const float4*)&Wup[k * 128 + jb + jg * 4];
        acc[jg].x += a * w.x; acc[jg].y += a * w.y;
        acc[jg].z += a * w.z; acc[jg].w += a * w.w;
      }
    }
    #pragma unroll
    for (int jg = 0; jg < 4; jg++)
      *(float4*)&h[(n0 + n) * 128 + jb + jg * 4] = acc[jg];
  }
}

// ---------------- sc = einsum('nu,nv,uvk->nk') ----------------
// z[n,(u,v)] = f[n,u]*a[n,v]; sc = z @ Wskip([1280,128])
__global__ __launch_bounds__(128) void k_sc(const float* __restrict__ feats,
                                            const float* __restrict__ attrs,
                                            const float* __restrict__ Wskip,
                                            float* __restrict__ sc_out) {
  __shared__ float sZ[1280][8];   // [j][node]  40KB
  int tid = threadIdx.x;
  int n0 = blockIdx.x * 8;        // N divisible: 1250*8
  for (int idx = tid; idx < 1280 * 8; idx += 128) {
    int j = idx >> 3, nn = idx & 7;
    int u = j / 10, v = j - u * 10;
    sZ[j][nn] = feats[(n0 + nn) * 128 + u] * attrs[(n0 + nn) * 10 + v];
  }
  __syncthreads();
  int k = tid;
  float acc[8] = {};
  for (int j = 0; j < 1280; j++) {
    float w = Wskip[j * 128 + k];
    float4 z0 = *(const float4*)&sZ[j][0];
    float4 z1 = *(const float4*)&sZ[j][4];
    acc[0] += z0.x * w; acc[1] += z0.y * w; acc[2] += z0.z * w; acc[3] += z0.w * w;
    acc[4] += z1.x * w; acc[5] += z1.y * w; acc[6] += z1.z * w; acc[7] += z1.w * w;
  }
  #pragma unroll
  for (int nn = 0; nn < 8; nn++)
    sc_out[(n0 + nn) * 128 + k] = acc[nn];
}

// ---------------- fused edge MLP -> tpw (bf16 [E,384]) ----------------
__device__ __forceinline__ void layer64(const float (*In)[65], const float* __restrict__ W,
                                        float (*Out)[65], int e, int q) {
  float4 acc[4] = {};
  int j0 = q * 16;
  for (int k = 0; k < 64; k++) {
    float a = In[e][k];
    #pragma unroll
    for (int jg = 0; jg < 4; jg++) {
      float4 w = *(const float4*)&W[k * 64 + j0 + jg * 4];
      acc[jg].x += a * w.x; acc[jg].y += a * w.y;
      acc[jg].z += a * w.z; acc[jg].w += a * w.w;
    }
  }
  #pragma unroll
  for (int jg = 0; jg < 4; jg++) {
    Out[e][j0 + jg * 4 + 0] = silu_f(acc[jg].x);
    Out[e][j0 + jg * 4 + 1] = silu_f(acc[jg].y);
    Out[e][j0 + jg * 4 + 2] = silu_f(acc[jg].z);
    Out[e][j0 + jg * 4 + 3] = silu_f(acc[jg].w);
  }
}

__global__ __launch_bounds__(256) void k_mlp(const float* __restrict__ ef,
                                             const float* __restrict__ W1,
                                             const float* __restrict__ W2,
                                             const float* __restrict__ W3,
                                             const float* __restrict__ W4,
                                             unsigned short* __restrict__ tpw) {
  __shared__ float sEF[64][9];
  __shared__ float sA[64][65];
  __shared__ float sB[64][65];
  int tid = threadIdx.x;
  int e0 = blockIdx.x * 64;       // E divisible: 2000*64
  for (int i = tid; i < 64 * 8; i += 256) sEF[i >> 3][i & 7] = ef[e0 * 8 + i];
  __syncthreads();
  int e = tid >> 2, q = tid & 3;
  // L1: 8 -> 64
  {
    float efr[8];
    #pragma unroll
    for (int i = 0; i < 8; i++) efr[i] = sEF[e][i];
    #pragma unroll
    for (int jj = 0; jj < 16; jj++) {
      int j = q * 16 + jj;
      float acc = 0.f;
      #pragma unroll
      for (int i = 0; i < 8; i++) acc += efr[i] * W1[i * 64 + j];
      sA[e][j] = silu_f(acc);
    }
  }
  __syncthreads();
  layer64(sA, W2, sB, e, q);   // L2
  __syncthreads();
  layer64(sB, W3, sA, e, q);   // L3
  __syncthreads();
  // L4: 64 -> 384 (no activation), bf16 out
  int jbase = q * 96;
  #pragma unroll 1
  for (int jg = 0; jg < 24; jg += 4) {
    float4 acc[4] = {};
    for (int k = 0; k < 64; k++) {
      float a = sA[e][k];
      #pragma unroll
      for (int t = 0; t < 4; t++) {
        float4 w = *(const float4*)&W4[k * 384 + jbase + (jg + t) * 4];
        acc[t].x += a * w.x; acc[t].y += a * w.y;
        acc[t].z += a * w.z; acc[t].w += a * w.w;
      }
    }
    #pragma unroll
    for (int t = 0; t < 4; t++) {
      uint2 p;
      p.x = (unsigned)f2bf(acc[t].x) | ((unsigned)f2bf(acc[t].y) << 16);
      p.y = (unsigned)f2bf(acc[t].z) | ((unsigned)f2bf(acc[t].w) << 16);
      *(uint2*)&tpw[(e0 + e) * 384 + jbase + (jg + t) * 4] = p;
    }
  }
}

// ---------------- CSR build (counting sort by receiver) ----------------
__global__ void k_hist(const int* __restrict__ recv, int* __restrict__ counts) {
  int e = blockIdx.x * 256 + threadIdx.x;
  if (e < N_EDGES) atomicAdd(&counts[recv[e]], 1);
}

__global__ __launch_bounds__(1024) void k_scan(const int* __restrict__ counts,
                                               int* __restrict__ offsets,
                                               int* __restrict__ cursor) {
  __shared__ int part[1024];
  int tid = threadIdx.x;
  int base = tid * 10;
  int local[10]; int s = 0;
  #pragma unroll
  for (int i = 0; i < 10; i++) {
    int idx = base + i;
    int c = (idx < N_NODES) ? counts[idx] : 0;
    local[i] = s; s += c;
  }
  part[tid] = s;
  __syncthreads();
  for (int off = 1; off < 1024; off <<= 1) {
    int v = (tid >= off) ? part[tid - off] : 0;
    __syncthreads();
    part[tid] += v;
    __syncthreads();
  }
  int pre = (tid > 0) ? part[tid - 1] : 0;
  #pragma unroll
  for (int i = 0; i < 10; i++) {
    int idx = base + i;
    if (idx < N_NODES) { int o = pre + local[i]; offsets[idx] = o; cursor[idx] = o; }
  }
  if (tid == 1023) offsets[N_NODES] = part[1023];
}

__global__ void k_scatter(const int* __restrict__ recv, int* __restrict__ cursor,
                          int* __restrict__ order) {
  int e = blockIdx.x * 256 + threadIdx.x;
  if (e < N_EDGES) {
    int idx = atomicAdd(&cursor[recv[e]], 1);
    order[idx] = e;
  }
}

// ---------------- per-node: gather edges, conv_tp accumulate, linear ----------------
__global__ __launch_bounds__(128) void k_node(
    const float* __restrict__ h, const unsigned short* __restrict__ tpw,
    const float* __restrict__ yr, const float* __restrict__ yi,
    const int* __restrict__ send, const int* __restrict__ offsets,
    const int* __restrict__ order,
    const float* __restrict__ Wl0, const float* __restrict__ Wl1,
    const float* __restrict__ Wl2,
    float* __restrict__ out) {
  __shared__ float sMsg[128][24];   // [u][0..8]=real, [12..20]=imag (16B aligned blocks)
  int u = threadIdx.x;
  int n = blockIdx.x;
  float mr[9] = {}, mi[9] = {};
  int e0 = offsets[n], e1 = offsets[n + 1];
  for (int jj = e0; jj < e1; jj++) {
    int e = order[jj];
    int s = send[e];
    float xv = h[s * 128 + u];
    __hip_bfloat16 b0 = *(const __hip_bfloat16*)&tpw[e * 384 + u];
    __hip_bfloat16 b1 = *(const __hip_bfloat16*)&tpw[e * 384 + 128 + u];
    __hip_bfloat16 b2 = *(const __hip_bfloat16*)&tpw[e * 384 + 256 + u];
    float xw0 = xv * __bfloat162float(b0);
    float xw1 = xv * __bfloat162float(b1);
    float xw2 = xv * __bfloat162float(b2);
    const float* yre = &yr[e * 9];
    const float* yie = &yi[e * 9];
    mr[0] += xw0 * yre[0]; mi[0] += xw0 * yie[0];
    #pragma unroll
    for (int m = 1; m < 4; m++) { mr[m] += xw1 * yre[m]; mi[m] += xw1 * yie[m]; }
    #pragma unroll
    for (int m = 4; m < 9; m++) { mr[m] += xw2 * yre[m]; mi[m] += xw2 * yie[m]; }
  }
  #pragma unroll
  for (int m = 0; m < 9; m++) { sMsg[u][m] = mr[m]; sMsg[u][12 + m] = mi[m]; }
  __syncthreads();
  int k = u;
  float ar[9] = {}, ai[9] = {};
  for (int uu = 0; uu < 128; uu++) {
    float w0 = Wl0[uu * 128 + k];
    float w1 = Wl1[uu * 128 + k];
    float w2 = Wl2[uu * 128 + k];
    float4 r0 = *(const float4*)&sMsg[uu][0];
    float4 r1 = *(const float4*)&sMsg[uu][4];
    float  r2 = sMsg[uu][8];
    float4 i0 = *(const float4*)&sMsg[uu][12];
    float4 i1 = *(const float4*)&sMsg[uu][16];
    float  i2 = sMsg[uu][20];
    ar[0] += r0.x * w0; ai[0] += i0.x * w0;
    ar[1] += r0.y * w1; ai[1] += i0.y * w1;
    ar[2] += r0.z * w1; ai[2] += i0.z * w1;
    ar[3] += r0.w * w1; ai[3] += i0.w * w1;
    ar[4] += r1.x * w2; ai[4] += i1.x * w2;
    ar[5] += r1.y * w2; ai[5] += i1.y * w2;
    ar[6] += r1.z * w2; ai[6] += i1.z * w2;
    ar[7] += r1.w * w2; ai[7] += i1.w * w2;
    ar[8] += r2  * w2;  ai[8] += i2  * w2;
  }
  int base = n * 1152 + k * 9;
  #pragma unroll
  for (int m = 0; m < 9; m++) out[base + m] = ar[m];
  #pragma unroll
  for (int m = 0; m < 9; m++) out[11520000 + base + m] = ai[m];
}

// ---------------- launch ----------------
extern "C" void kernel_launch(void* const* d_in, const int* in_sizes, int n_in,
                              void* d_out, int out_size, void* d_ws, size_t ws_size,
                              hipStream_t stream) {
  const float* node_attrs = (const float*)d_in[0];
  const float* node_feats = (const float*)d_in[1];
  const float* ear   = (const float*)d_in[2];
  const float* eai   = (const float*)d_in[3];
  const float* ef    = (const float*)d_in[4];
  const int*   eidx  = (const int*)d_in[5];
  const float* Wup   = (const float*)d_in[6];
  const float* Wskip = (const float*)d_in[7];
  const float* W1    = (const float*)d_in[8];
  const float* W2    = (const float*)d_in[9];
  const float* W3    = (const float*)d_in[10];
  const float* W4    = (const float*)d_in[11];
  const float* Wl0   = (const float*)d_in[12];
  const float* Wl1   = (const float*)d_in[13];
  const float* Wl2   = (const float*)d_in[14];
  float* out = (float*)d_out;

  // workspace layout (bytes):
  //   h: 0 .. 5,120,000   | tpw bf16: 5,120,000 .. 103,424,000
  //   counts / offsets / cursor / order   (total ~104.1 MB)
  char* ws = (char*)d_ws;
  float*          h       = (float*)ws;
  unsigned short* tpw     = (unsigned short*)(ws + 5120000);
  int*            counts  = (int*)(ws + 103424000);
  int*            offsets = (int*)(ws + 103464192);
  int*            cursor  = (int*)(ws + 103504384);
  int*            order   = (int*)(ws + 103544576);

  const int* send = eidx;
  const int* recv = eidx + N_EDGES;

  hipMemsetAsync(counts, 0, N_NODES * sizeof(int), stream);
  k_hist<<<dim3(500), dim3(256), 0, stream>>>(recv, counts);
  k_scan<<<dim3(1), dim3(1024), 0, stream>>>(counts, offsets, cursor);
  k_scatter<<<dim3(500), dim3(256), 0, stream>>>(recv, cursor, order);
  k_h<<<dim3(313), dim3(256), 0, stream>>>(node_feats, Wup, h);
  k_sc<<<dim3(1250), dim3(128), 0, stream>>>(node_feats, node_attrs, Wskip,
                                             out + 2 * 11520000);
  k_mlp<<<dim3(2000), dim3(256), 0, stream>>>(ef, W1, W2, W3, W4, tpw);
  k_node<<<dim3(10000), dim3(128), 0, stream>>>(h, tpw, ear, eai, send, offsets,
                                                order, Wl0, Wl1, Wl2, out);
  (void)in_sizes; (void)n_in; (void)out_size; (void)ws_size;
}

// Round 2
// 611.412 us; speedup vs baseline: 3.3980x; 3.3980x over previous
//
#include <hip/hip_runtime.h>
#include <hip/hip_bf16.h>

#define N_NODES 10000
#define N_EDGES 128000
#define C_DIM   128

// ---------------- helpers ----------------

__device__ __forceinline__ float silu_f(float x) {
  return x / (1.f + __expf(-x));
}

__device__ __forceinline__ unsigned short f2bf(float x) {
  __hip_bfloat16 b = __float2bfloat16(x);
  return *(unsigned short*)&b;
}

// ---------------- h = feats @ W_up  [N,128]x[128,128] ----------------
__global__ __launch_bounds__(256) void k_h(const float* __restrict__ feats,
                                           const float* __restrict__ Wup,
                                           float* __restrict__ h) {
  __shared__ float sF[32][129];
  int tid = threadIdx.x;
  int n0 = blockIdx.x * 32;
  int nmax = N_NODES - n0; if (nmax > 32) nmax = 32;
  for (int i = tid; i < 32 * 128; i += 256) {
    int nn = i >> 7, kk = i & 127;
    sF[nn][kk] = (nn < nmax) ? feats[(n0 + nn) * 128 + kk] : 0.f;
  }
  __syncthreads();
  int n = tid >> 3;          // 0..31
  int jb = (tid & 7) * 16;   // 0..112
  if (n < nmax) {
    float4 acc[4] = {};
    for (int k = 0; k < 128; k++) {
      float a = sF[n][k];
      #pragma unroll
      for (int jg = 0; jg < 4; jg++) {
        float4 w = *(const float4*)&Wup[k * 128 + jb + jg * 4];
        acc[jg].x += a * w.x; acc[jg].y += a * w.y;
        acc[jg].z += a * w.z; acc[jg].w += a * w.w;
      }
    }
    #pragma unroll
    for (int jg = 0; jg < 4; jg++)
      *(float4*)&h[(n0 + n) * 128 + jb + jg * 4] = acc[jg];
  }
}

// ---------------- sc = einsum('nu,nv,uvk->nk') ----------------
__global__ __launch_bounds__(128) void k_sc(const float* __restrict__ feats,
                                            const float* __restrict__ attrs,
                                            const float* __restrict__ Wskip,
                                            float* __restrict__ sc_out) {
  __shared__ float sZ[1280][8];   // [j][node]  40KB
  int tid = threadIdx.x;
  int n0 = blockIdx.x * 8;        // N divisible: 1250*8
  for (int idx = tid; idx < 1280 * 8; idx += 128) {
    int j = idx >> 3, nn = idx & 7;
    int u = j / 10, v = j - u * 10;
    sZ[j][nn] = feats[(n0 + nn) * 128 + u] * attrs[(n0 + nn) * 10 + v];
  }
  __syncthreads();
  int k = tid;
  float acc[8] = {};
  for (int j = 0; j < 1280; j++) {
    float w = Wskip[j * 128 + k];
    float4 z0 = *(const float4*)&sZ[j][0];
    float4 z1 = *(const float4*)&sZ[j][4];
    acc[0] += z0.x * w; acc[1] += z0.y * w; acc[2] += z0.z * w; acc[3] += z0.w * w;
    acc[4] += z1.x * w; acc[5] += z1.y * w; acc[6] += z1.z * w; acc[7] += z1.w * w;
  }
  #pragma unroll
  for (int nn = 0; nn < 8; nn++)
    sc_out[(n0 + nn) * 128 + k] = acc[nn];
}

// ---------------- fused edge MLP v2: LDS-staged, register-tiled ----------------
// 128 edges/block, 256 threads. Activations k-major in LDS: sX[k][e].
// Thread tile: 4 edges x 8 outputs. Weights staged in LDS (W4 in 64-col chunks).
__global__ __launch_bounds__(256) void k_mlp(const float* __restrict__ ef,
                                             const float* __restrict__ W1,
                                             const float* __restrict__ W2,
                                             const float* __restrict__ W3,
                                             const float* __restrict__ W4,
                                             unsigned short* __restrict__ tpw) {
  __shared__ float sX[64][128];   // 32 KB activations, k-major
  __shared__ float sW[64][64];    // 16 KB weight chunk [k][j]
  // alias sEF / sW1 into sW (used only before W2 is staged)
  float (*sEF)[128] = (float (*)[128])&sW[0][0];   // 8 x 128 = 4 KB
  float (*sW1)[64]  = (float (*)[64])&sW[16][0];   // 8 x 64  = 2 KB

  int tid = threadIdx.x;
  int e0 = blockIdx.x * 128;      // E = 1000 * 128

  // --- stage ef (transposed) + W1 ---
  {
    float4 v = *(const float4*)&ef[e0 * 8 + tid * 4];
    int e = tid >> 1;
    int i0 = (tid & 1) * 4;
    sEF[i0 + 0][e] = v.x; sEF[i0 + 1][e] = v.y;
    sEF[i0 + 2][e] = v.z; sEF[i0 + 3][e] = v.w;
  }
  if (tid < 128) {
    float4 v = *(const float4*)&W1[tid * 4];
    int r = tid >> 4, c = (tid & 15) * 4;
    *(float4*)&sW1[r][c] = v;
  }
  __syncthreads();

  int eg = tid & 31, og = tid >> 5;   // og 0..7
  int ecol = eg * 4, jrow = og * 8;
  float acc[8][4];

  // --- L1: 8 -> 64 ---
  #pragma unroll
  for (int j = 0; j < 8; j++)
    #pragma unroll
    for (int e = 0; e < 4; e++) acc[j][e] = 0.f;
  #pragma unroll
  for (int k = 0; k < 8; k++) {
    float4 av = *(const float4*)&sEF[k][ecol];
    float a[4] = {av.x, av.y, av.z, av.w};
    float4 b0 = *(const float4*)&sW1[k][jrow];
    float4 b1 = *(const float4*)&sW1[k][jrow + 4];
    float b[8] = {b0.x, b0.y, b0.z, b0.w, b1.x, b1.y, b1.z, b1.w};
    #pragma unroll
    for (int j = 0; j < 8; j++)
      #pragma unroll
      for (int e = 0; e < 4; e++) acc[j][e] += a[e] * b[j];
  }
  __syncthreads();   // sEF/sW1 reads done
  // write L1 (silu) to sX; stage W2 into sW
  #pragma unroll
  for (int j = 0; j < 8; j++) {
    float4 o = {silu_f(acc[j][0]), silu_f(acc[j][1]),
                silu_f(acc[j][2]), silu_f(acc[j][3])};
    *(float4*)&sX[jrow + j][ecol] = o;
  }
  #pragma unroll
  for (int i = 0; i < 4; i++) {
    int idx = i * 256 + tid;
    float4 v = *(const float4*)&W2[idx * 4];
    int r = idx >> 4, c = (idx & 15) * 4;
    *(float4*)&sW[r][c] = v;
  }
  __syncthreads();

  // --- L2 / L3: 64 -> 64, in-place on sX ---
  #pragma unroll 1
  for (int layer = 0; layer < 2; layer++) {
    #pragma unroll
    for (int j = 0; j < 8; j++)
      #pragma unroll
      for (int e = 0; e < 4; e++) acc[j][e] = 0.f;
    for (int k = 0; k < 64; k++) {
      float4 av = *(const float4*)&sX[k][ecol];
      float a[4] = {av.x, av.y, av.z, av.w};
      float4 b0 = *(const float4*)&sW[k][jrow];
      float4 b1 = *(const float4*)&sW[k][jrow + 4];
      float b[8] = {b0.x, b0.y, b0.z, b0.w, b1.x, b1.y, b1.z, b1.w};
      #pragma unroll
      for (int j = 0; j < 8; j++)
        #pragma unroll
        for (int e = 0; e < 4; e++) acc[j][e] += a[e] * b[j];
    }
    __syncthreads();   // all reads of sX/sW done
    #pragma unroll
    for (int j = 0; j < 8; j++) {
      float4 o = {silu_f(acc[j][0]), silu_f(acc[j][1]),
                  silu_f(acc[j][2]), silu_f(acc[j][3])};
      *(float4*)&sX[jrow + j][ecol] = o;
    }
    // stage next weights: W3 (layer 0) or W4 chunk 0 (layer 1)
    const float* Wn = (layer == 0) ? W3 : W4;
    #pragma unroll
    for (int i = 0; i < 4; i++) {
      int idx = i * 256 + tid;
      int r = idx >> 4, c = (idx & 15) * 4;
      float4 v = (layer == 0) ? *(const float4*)&Wn[r * 64 + c]
                              : *(const float4*)&Wn[r * 384 + c];
      *(float4*)&sW[r][c] = v;
    }
    __syncthreads();
  }

  // --- L4: 64 -> 384 in 6 chunks of 64 cols, bf16 out ---
  #pragma unroll 1
  for (int ch = 0; ch < 6; ch++) {
    #pragma unroll
    for (int j = 0; j < 8; j++)
      #pragma unroll
      for (int e = 0; e < 4; e++) acc[j][e] = 0.f;
    for (int k = 0; k < 64; k++) {
      float4 av = *(const float4*)&sX[k][ecol];
      float a[4] = {av.x, av.y, av.z, av.w};
      float4 b0 = *(const float4*)&sW[k][jrow];
      float4 b1 = *(const float4*)&sW[k][jrow + 4];
      float b[8] = {b0.x, b0.y, b0.z, b0.w, b1.x, b1.y, b1.z, b1.w};
      #pragma unroll
      for (int j = 0; j < 8; j++)
        #pragma unroll
        for (int e = 0; e < 4; e++) acc[j][e] += a[e] * b[j];
    }
    #pragma unroll
    for (int e = 0; e < 4; e++) {
      uint4 p;
      p.x = (unsigned)f2bf(acc[0][e]) | ((unsigned)f2bf(acc[1][e]) << 16);
      p.y = (unsigned)f2bf(acc[2][e]) | ((unsigned)f2bf(acc[3][e]) << 16);
      p.z = (unsigned)f2bf(acc[4][e]) | ((unsigned)f2bf(acc[5][e]) << 16);
      p.w = (unsigned)f2bf(acc[6][e]) | ((unsigned)f2bf(acc[7][e]) << 16);
      *(uint4*)&tpw[(size_t)(e0 + ecol + e) * 384 + ch * 64 + jrow] = p;
    }
    if (ch < 5) {
      __syncthreads();   // sW reads done
      #pragma unroll
      for (int i = 0; i < 4; i++) {
        int idx = i * 256 + tid;
        int r = idx >> 4, c = (idx & 15) * 4;
        float4 v = *(const float4*)&W4[r * 384 + (ch + 1) * 64 + c];
        *(float4*)&sW[r][c] = v;
      }
      __syncthreads();
    }
  }
}

// ---------------- CSR build (counting sort by receiver) ----------------
__global__ void k_hist(const int* __restrict__ recv, int* __restrict__ counts) {
  int e = blockIdx.x * 256 + threadIdx.x;
  if (e < N_EDGES) atomicAdd(&counts[recv[e]], 1);
}

__global__ __launch_bounds__(1024) void k_scan(const int* __restrict__ counts,
                                               int* __restrict__ offsets,
                                               int* __restrict__ cursor) {
  __shared__ int part[1024];
  int tid = threadIdx.x;
  int base = tid * 10;
  int local[10]; int s = 0;
  #pragma unroll
  for (int i = 0; i < 10; i++) {
    int idx = base + i;
    int c = (idx < N_NODES) ? counts[idx] : 0;
    local[i] = s; s += c;
  }
  part[tid] = s;
  __syncthreads();
  for (int off = 1; off < 1024; off <<= 1) {
    int v = (tid >= off) ? part[tid - off] : 0;
    __syncthreads();
    part[tid] += v;
    __syncthreads();
  }
  int pre = (tid > 0) ? part[tid - 1] : 0;
  #pragma unroll
  for (int i = 0; i < 10; i++) {
    int idx = base + i;
    if (idx < N_NODES) { int o = pre + local[i]; offsets[idx] = o; cursor[idx] = o; }
  }
  if (tid == 1023) offsets[N_NODES] = part[1023];
}

__global__ void k_scatter(const int* __restrict__ recv, int* __restrict__ cursor,
                          int* __restrict__ order) {
  int e = blockIdx.x * 256 + threadIdx.x;
  if (e < N_EDGES) {
    int idx = atomicAdd(&cursor[recv[e]], 1);
    order[idx] = e;
  }
}

// ---------------- per-node: gather edges, conv_tp accumulate, linear ----------------
__global__ __launch_bounds__(128) void k_node(
    const float* __restrict__ h, const unsigned short* __restrict__ tpw,
    const float* __restrict__ yr, const float* __restrict__ yi,
    const int* __restrict__ send, const int* __restrict__ offsets,
    const int* __restrict__ order,
    const float* __restrict__ Wl0, const float* __restrict__ Wl1,
    const float* __restrict__ Wl2,
    float* __restrict__ out) {
  __shared__ float sMsg[128][24];   // [u][0..8]=real, [12..20]=imag
  int u = threadIdx.x;
  int n = blockIdx.x;
  float mr[9] = {}, mi[9] = {};
  int e0 = offsets[n], e1 = offsets[n + 1];
  for (int jj = e0; jj < e1; jj++) {
    int e = order[jj];
    int s = send[e];
    float xv = h[s * 128 + u];
    __hip_bfloat16 b0 = *(const __hip_bfloat16*)&tpw[e * 384 + u];
    __hip_bfloat16 b1 = *(const __hip_bfloat16*)&tpw[e * 384 + 128 + u];
    __hip_bfloat16 b2 = *(const __hip_bfloat16*)&tpw[e * 384 + 256 + u];
    float xw0 = xv * __bfloat162float(b0);
    float xw1 = xv * __bfloat162float(b1);
    float xw2 = xv * __bfloat162float(b2);
    const float* yre = &yr[e * 9];
    const float* yie = &yi[e * 9];
    mr[0] += xw0 * yre[0]; mi[0] += xw0 * yie[0];
    #pragma unroll
    for (int m = 1; m < 4; m++) { mr[m] += xw1 * yre[m]; mi[m] += xw1 * yie[m]; }
    #pragma unroll
    for (int m = 4; m < 9; m++) { mr[m] += xw2 * yre[m]; mi[m] += xw2 * yie[m]; }
  }
  #pragma unroll
  for (int m = 0; m < 9; m++) { sMsg[u][m] = mr[m]; sMsg[u][12 + m] = mi[m]; }
  __syncthreads();
  int k = u;
  float ar[9] = {}, ai[9] = {};
  for (int uu = 0; uu < 128; uu++) {
    float w0 = Wl0[uu * 128 + k];
    float w1 = Wl1[uu * 128 + k];
    float w2 = Wl2[uu * 128 + k];
    float4 r0 = *(const float4*)&sMsg[uu][0];
    float4 r1 = *(const float4*)&sMsg[uu][4];
    float  r2 = sMsg[uu][8];
    float4 i0 = *(const float4*)&sMsg[uu][12];
    float4 i1 = *(const float4*)&sMsg[uu][16];
    float  i2 = sMsg[uu][20];
    ar[0] += r0.x * w0; ai[0] += i0.x * w0;
    ar[1] += r0.y * w1; ai[1] += i0.y * w1;
    ar[2] += r0.z * w1; ai[2] += i0.z * w1;
    ar[3] += r0.w * w1; ai[3] += i0.w * w1;
    ar[4] += r1.x * w2; ai[4] += i1.x * w2;
    ar[5] += r1.y * w2; ai[5] += i1.y * w2;
    ar[6] += r1.z * w2; ai[6] += i1.z * w2;
    ar[7] += r1.w * w2; ai[7] += i1.w * w2;
    ar[8] += r2  * w2;  ai[8] += i2  * w2;
  }
  int base = n * 1152 + k * 9;
  #pragma unroll
  for (int m = 0; m < 9; m++) out[base + m] = ar[m];
  #pragma unroll
  for (int m = 0; m < 9; m++) out[11520000 + base + m] = ai[m];
}

// ---------------- launch ----------------
extern "C" void kernel_launch(void* const* d_in, const int* in_sizes, int n_in,
                              void* d_out, int out_size, void* d_ws, size_t ws_size,
                              hipStream_t stream) {
  const float* node_attrs = (const float*)d_in[0];
  const float* node_feats = (const float*)d_in[1];
  const float* ear   = (const float*)d_in[2];
  const float* eai   = (const float*)d_in[3];
  const float* ef    = (const float*)d_in[4];
  const int*   eidx  = (const int*)d_in[5];
  const float* Wup   = (const float*)d_in[6];
  const float* Wskip = (const float*)d_in[7];
  const float* W1    = (const float*)d_in[8];
  const float* W2    = (const float*)d_in[9];
  const float* W3    = (const float*)d_in[10];
  const float* W4    = (const float*)d_in[11];
  const float* Wl0   = (const float*)d_in[12];
  const float* Wl1   = (const float*)d_in[13];
  const float* Wl2   = (const float*)d_in[14];
  float* out = (float*)d_out;

  char* ws = (char*)d_ws;
  float*          h       = (float*)ws;
  unsigned short* tpw     = (unsigned short*)(ws + 5120000);
  int*            counts  = (int*)(ws + 103424000);
  int*            offsets = (int*)(ws + 103464192);
  int*            cursor  = (int*)(ws + 103504384);
  int*            order   = (int*)(ws + 103544576);

  const int* send = eidx;
  const int* recv = eidx + N_EDGES;

  hipMemsetAsync(counts, 0, N_NODES * sizeof(int), stream);
  k_hist<<<dim3(500), dim3(256), 0, stream>>>(recv, counts);
  k_scan<<<dim3(1), dim3(1024), 0, stream>>>(counts, offsets, cursor);
  k_scatter<<<dim3(500), dim3(256), 0, stream>>>(recv, cursor, order);
  k_h<<<dim3(313), dim3(256), 0, stream>>>(node_feats, Wup, h);
  k_sc<<<dim3(1250), dim3(128), 0, stream>>>(node_feats, node_attrs, Wskip,
                                             out + 2 * 11520000);
  k_mlp<<<dim3(1000), dim3(256), 0, stream>>>(ef, W1, W2, W3, W4, tpw);
  k_node<<<dim3(10000), dim3(128), 0, stream>>>(h, tpw, ear, eai, send, offsets,
                                                order, Wl0, Wl1, Wl2, out);
  (void)in_sizes; (void)n_in; (void)out_size; (void)ws_size;
}

// Round 3
// 510.692 us; speedup vs baseline: 4.0682x; 1.1972x over previous
//
#include <hip/hip_runtime.h>
#include <hip/hip_bf16.h>

#define N_NODES 10000
#define N_EDGES 128000
#define C_DIM   128

typedef __attribute__((ext_vector_type(8))) short bf16x8;
typedef __attribute__((ext_vector_type(4))) float f32x4;

// ---------------- helpers ----------------

__device__ __forceinline__ float silu_f(float x) {
  return x / (1.f + __expf(-x));
}

__device__ __forceinline__ unsigned short f2bf(float x) {
  __hip_bfloat16 b = __float2bfloat16(x);
  return *(unsigned short*)&b;
}

__device__ __forceinline__ bf16x8 pack8(float4 lo, float4 hi) {
  bf16x8 r;
  r[0] = (short)f2bf(lo.x); r[1] = (short)f2bf(lo.y);
  r[2] = (short)f2bf(lo.z); r[3] = (short)f2bf(lo.w);
  r[4] = (short)f2bf(hi.x); r[5] = (short)f2bf(hi.y);
  r[6] = (short)f2bf(hi.z); r[7] = (short)f2bf(hi.w);
  return r;
}

// ---------------- h = feats @ W_up  [N,128]x[128,128] ----------------
__global__ __launch_bounds__(256) void k_h(const float* __restrict__ feats,
                                           const float* __restrict__ Wup,
                                           float* __restrict__ h) {
  __shared__ float sF[32][129];
  int tid = threadIdx.x;
  int n0 = blockIdx.x * 32;
  int nmax = N_NODES - n0; if (nmax > 32) nmax = 32;
  for (int i = tid; i < 32 * 128; i += 256) {
    int nn = i >> 7, kk = i & 127;
    sF[nn][kk] = (nn < nmax) ? feats[(n0 + nn) * 128 + kk] : 0.f;
  }
  __syncthreads();
  int n = tid >> 3;
  int jb = (tid & 7) * 16;
  if (n < nmax) {
    float4 acc[4] = {};
    for (int k = 0; k < 128; k++) {
      float a = sF[n][k];
      #pragma unroll
      for (int jg = 0; jg < 4; jg++) {
        float4 w = *(const float4*)&Wup[k * 128 + jb + jg * 4];
        acc[jg].x += a * w.x; acc[jg].y += a * w.y;
        acc[jg].z += a * w.z; acc[jg].w += a * w.w;
      }
    }
    #pragma unroll
    for (int jg = 0; jg < 4; jg++)
      *(float4*)&h[(n0 + n) * 128 + jb + jg * 4] = acc[jg];
  }
}

// ---------------- weight convert/transpose (bf16) ----------------
// wbT[k][v*128+u] = Wskip[(u*10+v)*128+k]   (128 x 1280)
// wlT[l][k][u]    = Wl_l[u*128+k]           (3 x 128 x 128)
__global__ void k_wcvt(const float* __restrict__ Wskip,
                       const float* __restrict__ Wl0,
                       const float* __restrict__ Wl1,
                       const float* __restrict__ Wl2,
                       unsigned short* __restrict__ wbT,
                       unsigned short* __restrict__ wlT) {
  int idx = blockIdx.x * 256 + threadIdx.x;
  if (idx < 163840) {
    int j = idx >> 7, k = idx & 127;
    int u = j / 10, v = j - u * 10;
    wbT[k * 1280 + v * 128 + u] = f2bf(Wskip[idx]);
  } else if (idx < 163840 + 49152) {
    int t = idx - 163840;
    int l = t >> 14, r = t & 16383;
    int u = r >> 7, k = r & 127;
    const float* W = (l == 0) ? Wl0 : (l == 1) ? Wl1 : Wl2;
    wlT[(l * 128 + k) * 128 + u] = f2bf(W[r]);
  }
}

// ---------------- sc via MFMA: [N x 1280]_z x [1280 x 128] ----------------
// z[n][v*128+u] = a[n,v]*f[n,u] built in registers. 32 rows/block, 4 waves
// each own 32 k-cols. K chunks of 128 (= one v each).
__global__ __launch_bounds__(256) void k_sc(const float* __restrict__ f,
                                            const float* __restrict__ at,
                                            const unsigned short* __restrict__ wbT,
                                            float* __restrict__ sc_out) {
  int tid = threadIdx.x;
  int w = tid >> 6, lane = tid & 63;
  int l15 = lane & 15, quad = lane >> 4;
  int n0 = blockIdx.x * 32;

  int nrow[2];
  #pragma unroll
  for (int t = 0; t < 2; t++) {
    int n = n0 + 16 * t + l15;
    nrow[t] = (n < N_NODES) ? n : (N_NODES - 1);
  }
  float4 fA[2][4][2];
  #pragma unroll
  for (int t = 0; t < 2; t++)
    #pragma unroll
    for (int ks = 0; ks < 4; ks++) {
      fA[t][ks][0] = *(const float4*)&f[nrow[t] * 128 + ks * 32 + quad * 8];
      fA[t][ks][1] = *(const float4*)&f[nrow[t] * 128 + ks * 32 + quad * 8 + 4];
    }

  f32x4 acc[2][2] = {};
  #pragma unroll 1
  for (int c = 0; c < 10; c++) {
    float av[2];
    #pragma unroll
    for (int t = 0; t < 2; t++) av[t] = at[nrow[t] * 10 + c];
    bf16x8 af[2][4];
    #pragma unroll
    for (int t = 0; t < 2; t++)
      #pragma unroll
      for (int ks = 0; ks < 4; ks++) {
        float4 lo = fA[t][ks][0], hi = fA[t][ks][1];
        lo.x *= av[t]; lo.y *= av[t]; lo.z *= av[t]; lo.w *= av[t];
        hi.x *= av[t]; hi.y *= av[t]; hi.z *= av[t]; hi.w *= av[t];
        af[t][ks] = pack8(lo, hi);
      }
    #pragma unroll
    for (int kt = 0; kt < 2; kt++) {
      int kcol = w * 32 + kt * 16 + l15;
      #pragma unroll
      for (int ks = 0; ks < 4; ks++) {
        bf16x8 bf = *(const bf16x8*)&wbT[kcol * 1280 + c * 128 + ks * 32 + quad * 8];
        #pragma unroll
        for (int t = 0; t < 2; t++)
          acc[t][kt] = __builtin_amdgcn_mfma_f32_16x16x32_bf16(af[t][ks], bf,
                                                               acc[t][kt], 0, 0, 0);
      }
    }
  }
  #pragma unroll
  for (int t = 0; t < 2; t++)
    #pragma unroll
    for (int kt = 0; kt < 2; kt++) {
      int kcol = w * 32 + kt * 16 + l15;
      #pragma unroll
      for (int reg = 0; reg < 4; reg++) {
        int n = n0 + 16 * t + quad * 4 + reg;
        if (n < N_NODES) sc_out[n * 128 + kcol] = acc[t][kt][reg];
      }
    }
}

// ---------------- fused edge MLP (LDS-staged, register-tiled) ----------------
__global__ __launch_bounds__(256) void k_mlp(const float* __restrict__ ef,
                                             const float* __restrict__ W1,
                                             const float* __restrict__ W2,
                                             const float* __restrict__ W3,
                                             const float* __restrict__ W4,
                                             unsigned short* __restrict__ tpw) {
  __shared__ float sX[64][128];
  __shared__ float sW[64][64];
  float (*sEF)[128] = (float (*)[128])&sW[0][0];
  float (*sW1)[64]  = (float (*)[64])&sW[16][0];

  int tid = threadIdx.x;
  int e0 = blockIdx.x * 128;

  {
    float4 v = *(const float4*)&ef[e0 * 8 + tid * 4];
    int e = tid >> 1;
    int i0 = (tid & 1) * 4;
    sEF[i0 + 0][e] = v.x; sEF[i0 + 1][e] = v.y;
    sEF[i0 + 2][e] = v.z; sEF[i0 + 3][e] = v.w;
  }
  if (tid < 128) {
    float4 v = *(const float4*)&W1[tid * 4];
    int r = tid >> 4, c = (tid & 15) * 4;
    *(float4*)&sW1[r][c] = v;
  }
  __syncthreads();

  int eg = tid & 31, og = tid >> 5;
  int ecol = eg * 4, jrow = og * 8;
  float acc[8][4];

  #pragma unroll
  for (int j = 0; j < 8; j++)
    #pragma unroll
    for (int e = 0; e < 4; e++) acc[j][e] = 0.f;
  #pragma unroll
  for (int k = 0; k < 8; k++) {
    float4 av = *(const float4*)&sEF[k][ecol];
    float a[4] = {av.x, av.y, av.z, av.w};
    float4 b0 = *(const float4*)&sW1[k][jrow];
    float4 b1 = *(const float4*)&sW1[k][jrow + 4];
    float b[8] = {b0.x, b0.y, b0.z, b0.w, b1.x, b1.y, b1.z, b1.w};
    #pragma unroll
    for (int j = 0; j < 8; j++)
      #pragma unroll
      for (int e = 0; e < 4; e++) acc[j][e] += a[e] * b[j];
  }
  __syncthreads();
  #pragma unroll
  for (int j = 0; j < 8; j++) {
    float4 o = {silu_f(acc[j][0]), silu_f(acc[j][1]),
                silu_f(acc[j][2]), silu_f(acc[j][3])};
    *(float4*)&sX[jrow + j][ecol] = o;
  }
  #pragma unroll
  for (int i = 0; i < 4; i++) {
    int idx = i * 256 + tid;
    float4 v = *(const float4*)&W2[idx * 4];
    int r = idx >> 4, c = (idx & 15) * 4;
    *(float4*)&sW[r][c] = v;
  }
  __syncthreads();

  #pragma unroll 1
  for (int layer = 0; layer < 2; layer++) {
    #pragma unroll
    for (int j = 0; j < 8; j++)
      #pragma unroll
      for (int e = 0; e < 4; e++) acc[j][e] = 0.f;
    for (int k = 0; k < 64; k++) {
      float4 av = *(const float4*)&sX[k][ecol];
      float a[4] = {av.x, av.y, av.z, av.w};
      float4 b0 = *(const float4*)&sW[k][jrow];
      float4 b1 = *(const float4*)&sW[k][jrow + 4];
      float b[8] = {b0.x, b0.y, b0.z, b0.w, b1.x, b1.y, b1.z, b1.w};
      #pragma unroll
      for (int j = 0; j < 8; j++)
        #pragma unroll
        for (int e = 0; e < 4; e++) acc[j][e] += a[e] * b[j];
    }
    __syncthreads();
    #pragma unroll
    for (int j = 0; j < 8; j++) {
      float4 o = {silu_f(acc[j][0]), silu_f(acc[j][1]),
                  silu_f(acc[j][2]), silu_f(acc[j][3])};
      *(float4*)&sX[jrow + j][ecol] = o;
    }
    const float* Wn = (layer == 0) ? W3 : W4;
    #pragma unroll
    for (int i = 0; i < 4; i++) {
      int idx = i * 256 + tid;
      int r = idx >> 4, c = (idx & 15) * 4;
      float4 v = (layer == 0) ? *(const float4*)&Wn[r * 64 + c]
                              : *(const float4*)&Wn[r * 384 + c];
      *(float4*)&sW[r][c] = v;
    }
    __syncthreads();
  }

  #pragma unroll 1
  for (int ch = 0; ch < 6; ch++) {
    #pragma unroll
    for (int j = 0; j < 8; j++)
      #pragma unroll
      for (int e = 0; e < 4; e++) acc[j][e] = 0.f;
    for (int k = 0; k < 64; k++) {
      float4 av = *(const float4*)&sX[k][ecol];
      float a[4] = {av.x, av.y, av.z, av.w};
      float4 b0 = *(const float4*)&sW[k][jrow];
      float4 b1 = *(const float4*)&sW[k][jrow + 4];
      float b[8] = {b0.x, b0.y, b0.z, b0.w, b1.x, b1.y, b1.z, b1.w};
      #pragma unroll
      for (int j = 0; j < 8; j++)
        #pragma unroll
        for (int e = 0; e < 4; e++) acc[j][e] += a[e] * b[j];
    }
    #pragma unroll
    for (int e = 0; e < 4; e++) {
      uint4 p;
      p.x = (unsigned)f2bf(acc[0][e]) | ((unsigned)f2bf(acc[1][e]) << 16);
      p.y = (unsigned)f2bf(acc[2][e]) | ((unsigned)f2bf(acc[3][e]) << 16);
      p.z = (unsigned)f2bf(acc[4][e]) | ((unsigned)f2bf(acc[5][e]) << 16);
      p.w = (unsigned)f2bf(acc[6][e]) | ((unsigned)f2bf(acc[7][e]) << 16);
      *(uint4*)&tpw[(size_t)(e0 + ecol + e) * 384 + ch * 64 + jrow] = p;
    }
    if (ch < 5) {
      __syncthreads();
      #pragma unroll
      for (int i = 0; i < 4; i++) {
        int idx = i * 256 + tid;
        int r = idx >> 4, c = (idx & 15) * 4;
        float4 v = *(const float4*)&W4[r * 384 + (ch + 1) * 64 + c];
        *(float4*)&sW[r][c] = v;
      }
      __syncthreads();
    }
  }
}

// ---------------- CSR build ----------------
__global__ void k_hist(const int* __restrict__ recv, int* __restrict__ counts) {
  int e = blockIdx.x * 256 + threadIdx.x;
  if (e < N_EDGES) atomicAdd(&counts[recv[e]], 1);
}

__global__ __launch_bounds__(1024) void k_scan(const int* __restrict__ counts,
                                               int* __restrict__ offsets,
                                               int* __restrict__ cursor) {
  __shared__ int part[1024];
  int tid = threadIdx.x;
  int base = tid * 10;
  int local[10]; int s = 0;
  #pragma unroll
  for (int i = 0; i < 10; i++) {
    int idx = base + i;
    int c = (idx < N_NODES) ? counts[idx] : 0;
    local[i] = s; s += c;
  }
  part[tid] = s;
  __syncthreads();
  for (int off = 1; off < 1024; off <<= 1) {
    int v = (tid >= off) ? part[tid - off] : 0;
    __syncthreads();
    part[tid] += v;
    __syncthreads();
  }
  int pre = (tid > 0) ? part[tid - 1] : 0;
  #pragma unroll
  for (int i = 0; i < 10; i++) {
    int idx = base + i;
    if (idx < N_NODES) { int o = pre + local[i]; offsets[idx] = o; cursor[idx] = o; }
  }
  if (tid == 1023) offsets[N_NODES] = part[1023];
}

__global__ void k_scatter(const int* __restrict__ recv, int* __restrict__ cursor,
                          int* __restrict__ order) {
  int e = blockIdx.x * 256 + threadIdx.x;
  if (e < N_EDGES) {
    int idx = atomicAdd(&cursor[recv[e]], 1);
    order[idx] = e;
  }
}

// ---------------- per-node gather: conv_tp + segment sum -> msg (bf16) ----------
// msg rows grouped by 8 nodes: group g rows [g*144, g*144+144):
//   rows 0..15  : l0  (i*2 + c)
//   rows 16..63 : l1  (16 + i*6 + c*3 + (m-1))
//   rows 64..143: l2  (64 + i*10 + c*5 + (m-4))
__device__ __forceinline__ void edge_acc(int e, int u,
    const float* __restrict__ h, const unsigned short* __restrict__ tpw,
    const float* __restrict__ yr, const float* __restrict__ yi,
    const int* __restrict__ send, float* mr, float* mi) {
  int s = send[e];
  float xv = h[s * 128 + u];
  __hip_bfloat16 b0 = *(const __hip_bfloat16*)&tpw[e * 384 + u];
  __hip_bfloat16 b1 = *(const __hip_bfloat16*)&tpw[e * 384 + 128 + u];
  __hip_bfloat16 b2 = *(const __hip_bfloat16*)&tpw[e * 384 + 256 + u];
  float xw0 = xv * __bfloat162float(b0);
  float xw1 = xv * __bfloat162float(b1);
  float xw2 = xv * __bfloat162float(b2);
  const float* yre = &yr[e * 9];
  const float* yie = &yi[e * 9];
  mr[0] += xw0 * yre[0]; mi[0] += xw0 * yie[0];
  #pragma unroll
  for (int m = 1; m < 4; m++) { mr[m] += xw1 * yre[m]; mi[m] += xw1 * yie[m]; }
  #pragma unroll
  for (int m = 4; m < 9; m++) { mr[m] += xw2 * yre[m]; mi[m] += xw2 * yie[m]; }
}

__global__ __launch_bounds__(128) void k_gather(
    const float* __restrict__ h, const unsigned short* __restrict__ tpw,
    const float* __restrict__ yr, const float* __restrict__ yi,
    const int* __restrict__ send, const int* __restrict__ offsets,
    const int* __restrict__ order,
    unsigned short* __restrict__ msg) {
  int u = threadIdx.x;
  int n = blockIdx.x;
  float mr[9] = {}, mi[9] = {};
  int e0 = offsets[n], e1 = offsets[n + 1];
  int jj = e0;
  for (; jj + 1 < e1; jj += 2) {
    int ea = order[jj];
    int eb = order[jj + 1];
    edge_acc(ea, u, h, tpw, yr, yi, send, mr, mi);
    edge_acc(eb, u, h, tpw, yr, yi, send, mr, mi);
  }
  if (jj < e1) {
    int ea = order[jj];
    edge_acc(ea, u, h, tpw, yr, yi, send, mr, mi);
  }
  int g = n >> 3, i = n & 7;
  unsigned short* mg = msg + (size_t)g * 144 * 128;
  // l0: rows i*2 + c
  mg[(i * 2 + 0) * 128 + u] = f2bf(mr[0]);
  mg[(i * 2 + 1) * 128 + u] = f2bf(mi[0]);
  // l1: rows 16 + i*6 + c*3 + (m-1)
  #pragma unroll
  for (int m = 1; m < 4; m++) {
    mg[(16 + i * 6 + (m - 1)) * 128 + u] = f2bf(mr[m]);
    mg[(16 + i * 6 + 3 + (m - 1)) * 128 + u] = f2bf(mi[m]);
  }
  // l2: rows 64 + i*10 + c*5 + (m-4)
  #pragma unroll
  for (int m = 4; m < 9; m++) {
    mg[(64 + i * 10 + (m - 4)) * 128 + u] = f2bf(mr[m]);
    mg[(64 + i * 10 + 5 + (m - 4)) * 128 + u] = f2bf(mi[m]);
  }
}

// ---------------- linear via MFMA: per 8-node group, 9 row-tiles x 8 k-tiles ----
__global__ __launch_bounds__(256) void k_lin(const unsigned short* __restrict__ msg,
                                             const unsigned short* __restrict__ wlT,
                                             float* __restrict__ out) {
  int tid = threadIdx.x;
  int w = tid >> 6, lane = tid & 63;
  int l15 = lane & 15, quad = lane >> 4;
  int g = blockIdx.x;

  bf16x8 bfr[3][2][4];
  #pragma unroll
  for (int l = 0; l < 3; l++)
    #pragma unroll
    for (int kt = 0; kt < 2; kt++)
      #pragma unroll
      for (int ks = 0; ks < 4; ks++) {
        int ncol = w * 32 + kt * 16 + l15;
        bfr[l][kt][ks] = *(const bf16x8*)&wlT[(l * 128 + ncol) * 128 + ks * 32 + quad * 8];
      }

  const unsigned short* mg = msg + (size_t)g * 144 * 128;

  #pragma unroll
  for (int tile = 0; tile < 9; tile++) {
    const int l = (tile == 0) ? 0 : (tile < 4) ? 1 : 2;
    const int rbase = tile * 16;
    bf16x8 af[4];
    #pragma unroll
    for (int ks = 0; ks < 4; ks++)
      af[ks] = *(const bf16x8*)&mg[(rbase + l15) * 128 + ks * 32 + quad * 8];
    f32x4 acc0 = {}, acc1 = {};
    #pragma unroll
    for (int ks = 0; ks < 4; ks++) {
      acc0 = __builtin_amdgcn_mfma_f32_16x16x32_bf16(af[ks], bfr[l][0][ks], acc0, 0, 0, 0);
      acc1 = __builtin_amdgcn_mfma_f32_16x16x32_bf16(af[ks], bfr[l][1][ks], acc1, 0, 0, 0);
    }
    #pragma unroll
    for (int reg = 0; reg < 4; reg++) {
      int r = rbase + quad * 4 + reg;   // local row 0..143
      int c, ni, m;
      if (tile == 0) { ni = (r & 15) >> 1; c = r & 1; m = 0; }
      else if (tile < 4) {
        int q = r - 16; ni = q / 6; int rem = q - ni * 6;
        c = rem >= 3; m = 1 + rem - (c ? 3 : 0);
      } else {
        int q = r - 64; ni = q / 10; int rem = q - ni * 10;
        c = rem >= 5; m = 4 + rem - (c ? 5 : 0);
      }
      int node = g * 8 + ni;
      float* ob = out + (size_t)c * 11520000 + node * 1152 + m;
      int k0 = w * 32 + l15;
      ob[(k0)      * 9] = acc0[reg];
      ob[(k0 + 16) * 9] = acc1[reg];
    }
  }
}

// ---------------- launch ----------------
extern "C" void kernel_launch(void* const* d_in, const int* in_sizes, int n_in,
                              void* d_out, int out_size, void* d_ws, size_t ws_size,
                              hipStream_t stream) {
  const float* node_attrs = (const float*)d_in[0];
  const float* node_feats = (const float*)d_in[1];
  const float* ear   = (const float*)d_in[2];
  const float* eai   = (const float*)d_in[3];
  const float* ef    = (const float*)d_in[4];
  const int*   eidx  = (const int*)d_in[5];
  const float* Wup   = (const float*)d_in[6];
  const float* Wskip = (const float*)d_in[7];
  const float* W1    = (const float*)d_in[8];
  const float* W2    = (const float*)d_in[9];
  const float* W3    = (const float*)d_in[10];
  const float* W4    = (const float*)d_in[11];
  const float* Wl0   = (const float*)d_in[12];
  const float* Wl1   = (const float*)d_in[13];
  const float* Wl2   = (const float*)d_in[14];
  float* out = (float*)d_out;

  // workspace layout (bytes):
  char* ws = (char*)d_ws;
  float*          h       = (float*)ws;                              //   5,120,000
  unsigned short* tpw     = (unsigned short*)(ws + 5120000);         //  98,304,000
  unsigned short* msg     = (unsigned short*)(ws + 103424000);       //  46,080,000
  unsigned short* wlT     = (unsigned short*)(ws + 149504000);       //      98,304
  unsigned short* wbT     = (unsigned short*)(ws + 149602304);       //     327,680
  int*            counts  = (int*)(ws + 149929984);
  int*            offsets = (int*)(ws + 149969984);
  int*            cursor  = (int*)(ws + 150010112);
  int*            order   = (int*)(ws + 150050112);

  const int* send = eidx;
  const int* recv = eidx + N_EDGES;

  hipMemsetAsync(counts, 0, N_NODES * sizeof(int), stream);
  k_hist<<<dim3(500), dim3(256), 0, stream>>>(recv, counts);
  k_scan<<<dim3(1), dim3(1024), 0, stream>>>(counts, offsets, cursor);
  k_scatter<<<dim3(500), dim3(256), 0, stream>>>(recv, cursor, order);
  k_wcvt<<<dim3(832), dim3(256), 0, stream>>>(Wskip, Wl0, Wl1, Wl2, wbT, wlT);
  k_h<<<dim3(313), dim3(256), 0, stream>>>(node_feats, Wup, h);
  k_sc<<<dim3(313), dim3(256), 0, stream>>>(node_feats, node_attrs, wbT,
                                            out + 2 * 11520000);
  k_mlp<<<dim3(1000), dim3(256), 0, stream>>>(ef, W1, W2, W3, W4, tpw);
  k_gather<<<dim3(10000), dim3(128), 0, stream>>>(h, tpw, ear, eai, send, offsets,
                                                  order, msg);
  k_lin<<<dim3(1250), dim3(256), 0, stream>>>(msg, wlT, out);
  (void)in_sizes; (void)n_in; (void)out_size; (void)ws_size;
}

// Round 4
// 433.207 us; speedup vs baseline: 4.7958x; 1.1789x over previous
//
#include <hip/hip_runtime.h>
#include <hip/hip_bf16.h>

#define N_NODES 10000
#define N_EDGES 128000
#define C_DIM   128

typedef __attribute__((ext_vector_type(8))) short bf16x8;
typedef __attribute__((ext_vector_type(4))) float f32x4;

// ---------------- helpers ----------------

__device__ __forceinline__ float silu_f(float x) {
  return x / (1.f + __expf(-x));
}

__device__ __forceinline__ unsigned short f2bf(float x) {
  __hip_bfloat16 b = __float2bfloat16(x);
  return *(unsigned short*)&b;
}

__device__ __forceinline__ bf16x8 pack8(float4 lo, float4 hi) {
  bf16x8 r;
  r[0] = (short)f2bf(lo.x); r[1] = (short)f2bf(lo.y);
  r[2] = (short)f2bf(lo.z); r[3] = (short)f2bf(lo.w);
  r[4] = (short)f2bf(hi.x); r[5] = (short)f2bf(hi.y);
  r[6] = (short)f2bf(hi.z); r[7] = (short)f2bf(hi.w);
  return r;
}

// ---------------- h = feats @ W_up  [N,128]x[128,128] ----------------
__global__ __launch_bounds__(256) void k_h(const float* __restrict__ feats,
                                           const float* __restrict__ Wup,
                                           float* __restrict__ h) {
  __shared__ float sF[32][129];
  int tid = threadIdx.x;
  int n0 = blockIdx.x * 32;
  int nmax = N_NODES - n0; if (nmax > 32) nmax = 32;
  for (int i = tid; i < 32 * 128; i += 256) {
    int nn = i >> 7, kk = i & 127;
    sF[nn][kk] = (nn < nmax) ? feats[(n0 + nn) * 128 + kk] : 0.f;
  }
  __syncthreads();
  int n = tid >> 3;
  int jb = (tid & 7) * 16;
  if (n < nmax) {
    float4 acc[4] = {};
    for (int k = 0; k < 128; k++) {
      float a = sF[n][k];
      #pragma unroll
      for (int jg = 0; jg < 4; jg++) {
        float4 w = *(const float4*)&Wup[k * 128 + jb + jg * 4];
        acc[jg].x += a * w.x; acc[jg].y += a * w.y;
        acc[jg].z += a * w.z; acc[jg].w += a * w.w;
      }
    }
    #pragma unroll
    for (int jg = 0; jg < 4; jg++)
      *(float4*)&h[(n0 + n) * 128 + jb + jg * 4] = acc[jg];
  }
}

// ---------------- weight convert/transpose (bf16) ----------------
// wbT[k][v*128+u] = Wskip[(u*10+v)*128+k]   (128 x 1280)
// wlT[l][k][u]    = Wl_l[u*128+k]           (3 x 128 x 128)
__global__ void k_wcvt(const float* __restrict__ Wskip,
                       const float* __restrict__ Wl0,
                       const float* __restrict__ Wl1,
                       const float* __restrict__ Wl2,
                       unsigned short* __restrict__ wbT,
                       unsigned short* __restrict__ wlT) {
  int idx = blockIdx.x * 256 + threadIdx.x;
  if (idx < 163840) {
    int j = idx >> 7, k = idx & 127;
    int u = j / 10, v = j - u * 10;
    wbT[k * 1280 + v * 128 + u] = f2bf(Wskip[idx]);
  } else if (idx < 163840 + 49152) {
    int t = idx - 163840;
    int l = t >> 14, r = t & 16383;
    int u = r >> 7, k = r & 127;
    const float* W = (l == 0) ? Wl0 : (l == 1) ? Wl1 : Wl2;
    wlT[(l * 128 + k) * 128 + u] = f2bf(W[r]);
  }
}

// MLP weights into MFMA-B-fragment-linear order:
// index = (ct*KS+ks)*512 + n*32 + (quad*8+j);  value = W[ks*32+t][ct*16+n]
__global__ void k_wcvt2(const float* __restrict__ W1, const float* __restrict__ W2,
                        const float* __restrict__ W3, const float* __restrict__ W4,
                        unsigned short* __restrict__ w1f, unsigned short* __restrict__ w2f,
                        unsigned short* __restrict__ w3f, unsigned short* __restrict__ w4f) {
  int idx = blockIdx.x * 256 + threadIdx.x;
  if (idx < 2048) {                        // W1: [8x64] padded K->32, 4 ct
    int ct = idx >> 9, r = idx & 511, n = r >> 5, t = r & 31;
    w1f[idx] = (t < 8) ? f2bf(W1[t * 64 + ct * 16 + n]) : (unsigned short)0;
  } else if (idx < 6144) {                 // W2: [64x64], 4 ct x 2 ks
    int j = idx - 2048;
    int ctks = j >> 9, r = j & 511, n = r >> 5, t = r & 31;
    int ct = ctks >> 1, ks = ctks & 1;
    w2f[j] = f2bf(W2[(ks * 32 + t) * 64 + ct * 16 + n]);
  } else if (idx < 10240) {                // W3
    int j = idx - 6144;
    int ctks = j >> 9, r = j & 511, n = r >> 5, t = r & 31;
    int ct = ctks >> 1, ks = ctks & 1;
    w3f[j] = f2bf(W3[(ks * 32 + t) * 64 + ct * 16 + n]);
  } else if (idx < 34816) {                // W4: [64x384], 24 ct x 2 ks
    int j = idx - 10240;
    int ctks = j >> 9, r = j & 511, n = r >> 5, t = r & 31;
    int ct = ctks >> 1, ks = ctks & 1;
    w4f[j] = f2bf(W4[(ks * 32 + t) * 384 + ct * 16 + n]);
  }
}

// ---------------- sc via MFMA: [N x 1280]_z x [1280 x 128] ----------------
__global__ __launch_bounds__(256) void k_sc(const float* __restrict__ f,
                                            const float* __restrict__ at,
                                            const unsigned short* __restrict__ wbT,
                                            float* __restrict__ sc_out) {
  int tid = threadIdx.x;
  int w = tid >> 6, lane = tid & 63;
  int l15 = lane & 15, quad = lane >> 4;
  int n0 = blockIdx.x * 32;

  int nrow[2];
  #pragma unroll
  for (int t = 0; t < 2; t++) {
    int n = n0 + 16 * t + l15;
    nrow[t] = (n < N_NODES) ? n : (N_NODES - 1);
  }
  float4 fA[2][4][2];
  #pragma unroll
  for (int t = 0; t < 2; t++)
    #pragma unroll
    for (int ks = 0; ks < 4; ks++) {
      fA[t][ks][0] = *(const float4*)&f[nrow[t] * 128 + ks * 32 + quad * 8];
      fA[t][ks][1] = *(const float4*)&f[nrow[t] * 128 + ks * 32 + quad * 8 + 4];
    }

  f32x4 acc[2][2] = {};
  #pragma unroll 1
  for (int c = 0; c < 10; c++) {
    float av[2];
    #pragma unroll
    for (int t = 0; t < 2; t++) av[t] = at[nrow[t] * 10 + c];
    bf16x8 af[2][4];
    #pragma unroll
    for (int t = 0; t < 2; t++)
      #pragma unroll
      for (int ks = 0; ks < 4; ks++) {
        float4 lo = fA[t][ks][0], hi = fA[t][ks][1];
        lo.x *= av[t]; lo.y *= av[t]; lo.z *= av[t]; lo.w *= av[t];
        hi.x *= av[t]; hi.y *= av[t]; hi.z *= av[t]; hi.w *= av[t];
        af[t][ks] = pack8(lo, hi);
      }
    #pragma unroll
    for (int kt = 0; kt < 2; kt++) {
      int kcol = w * 32 + kt * 16 + l15;
      #pragma unroll
      for (int ks = 0; ks < 4; ks++) {
        bf16x8 bf = *(const bf16x8*)&wbT[kcol * 1280 + c * 128 + ks * 32 + quad * 8];
        #pragma unroll
        for (int t = 0; t < 2; t++)
          acc[t][kt] = __builtin_amdgcn_mfma_f32_16x16x32_bf16(af[t][ks], bf,
                                                               acc[t][kt], 0, 0, 0);
      }
    }
  }
  #pragma unroll
  for (int t = 0; t < 2; t++)
    #pragma unroll
    for (int kt = 0; kt < 2; kt++) {
      int kcol = w * 32 + kt * 16 + l15;
      #pragma unroll
      for (int reg = 0; reg < 4; reg++) {
        int n = n0 + 16 * t + quad * 4 + reg;
        if (n < N_NODES) sc_out[n * 128 + kcol] = acc[t][kt][reg];
      }
    }
}

// ---------------- fused edge MLP via MFMA (bf16) ----------------
// 128 edges/block, 4 waves; wave w owns edge rows [w*32, w*32+32).
// Activations ping-pong sA<->sB, row-major bf16, rows padded to 72 (144B, 16B-aligned).
__global__ __launch_bounds__(256) void k_mlp(const float* __restrict__ ef,
                                             const unsigned short* __restrict__ w1f,
                                             const unsigned short* __restrict__ w2f,
                                             const unsigned short* __restrict__ w3f,
                                             const unsigned short* __restrict__ w4f,
                                             unsigned short* __restrict__ tpw) {
  __shared__ unsigned short sA[128][72];
  __shared__ unsigned short sB[128][72];
  int tid = threadIdx.x;
  int w = tid >> 6, lane = tid & 63;
  int l15 = lane & 15, quad = lane >> 4;
  int e0 = blockIdx.x * 128;
  int fragoff = l15 * 32 + quad * 8;
  int rb = w * 32;

  // ---- L1: 8 -> 64 (K padded to 32; only quad 0 carries data) ----
  {
    bf16x8 af[2];
    #pragma unroll
    for (int rt = 0; rt < 2; rt++) {
      bf16x8 a = {};
      if (quad == 0) {
        int e = e0 + rb + rt * 16 + l15;
        float4 lo = *(const float4*)&ef[e * 8];
        float4 hi = *(const float4*)&ef[e * 8 + 4];
        a = pack8(lo, hi);
      }
      af[rt] = a;
    }
    f32x4 ac[2][4] = {};
    #pragma unroll
    for (int ct = 0; ct < 4; ct++) {
      bf16x8 b = *(const bf16x8*)&w1f[ct * 512 + fragoff];
      ac[0][ct] = __builtin_amdgcn_mfma_f32_16x16x32_bf16(af[0], b, ac[0][ct], 0, 0, 0);
      ac[1][ct] = __builtin_amdgcn_mfma_f32_16x16x32_bf16(af[1], b, ac[1][ct], 0, 0, 0);
    }
    #pragma unroll
    for (int rt = 0; rt < 2; rt++)
      #pragma unroll
      for (int ct = 0; ct < 4; ct++)
        #pragma unroll
        for (int reg = 0; reg < 4; reg++)
          sA[rb + rt * 16 + quad * 4 + reg][ct * 16 + l15] =
              f2bf(silu_f(ac[rt][ct][reg]));
  }
  __syncthreads();

  // ---- L2: sA -> sB ; L3: sB -> sA ----
  #pragma unroll 1
  for (int layer = 0; layer < 2; layer++) {
    unsigned short (*src)[72] = (layer == 0) ? sA : sB;
    unsigned short (*dst)[72] = (layer == 0) ? sB : sA;
    const unsigned short* wf = (layer == 0) ? w2f : w3f;
    bf16x8 a2[2][2];
    #pragma unroll
    for (int rt = 0; rt < 2; rt++)
      #pragma unroll
      for (int ks = 0; ks < 2; ks++)
        a2[rt][ks] = *(const bf16x8*)&src[rb + rt * 16 + l15][ks * 32 + quad * 8];
    f32x4 ac[2][4] = {};
    #pragma unroll
    for (int ct = 0; ct < 4; ct++)
      #pragma unroll
      for (int ks = 0; ks < 2; ks++) {
        bf16x8 b = *(const bf16x8*)&wf[(ct * 2 + ks) * 512 + fragoff];
        ac[0][ct] = __builtin_amdgcn_mfma_f32_16x16x32_bf16(a2[0][ks], b, ac[0][ct], 0, 0, 0);
        ac[1][ct] = __builtin_amdgcn_mfma_f32_16x16x32_bf16(a2[1][ks], b, ac[1][ct], 0, 0, 0);
      }
    #pragma unroll
    for (int rt = 0; rt < 2; rt++)
      #pragma unroll
      for (int ct = 0; ct < 4; ct++)
        #pragma unroll
        for (int reg = 0; reg < 4; reg++)
          dst[rb + rt * 16 + quad * 4 + reg][ct * 16 + l15] =
              f2bf(silu_f(ac[rt][ct][reg]));
    __syncthreads();
  }

  // ---- L4: 64 -> 384, 6 chunks of 64 cols; C -> sB -> vectorized store ----
  bf16x8 a4[2][2];
  #pragma unroll
  for (int rt = 0; rt < 2; rt++)
    #pragma unroll
    for (int ks = 0; ks < 2; ks++)
      a4[rt][ks] = *(const bf16x8*)&sA[rb + rt * 16 + l15][ks * 32 + quad * 8];

  #pragma unroll 1
  for (int ch = 0; ch < 6; ch++) {
    f32x4 ac[2][4] = {};
    #pragma unroll
    for (int ct = 0; ct < 4; ct++)
      #pragma unroll
      for (int ks = 0; ks < 2; ks++) {
        bf16x8 b = *(const bf16x8*)&w4f[((ch * 4 + ct) * 2 + ks) * 512 + fragoff];
        ac[0][ct] = __builtin_amdgcn_mfma_f32_16x16x32_bf16(a4[0][ks], b, ac[0][ct], 0, 0, 0);
        ac[1][ct] = __builtin_amdgcn_mfma_f32_16x16x32_bf16(a4[1][ks], b, ac[1][ct], 0, 0, 0);
      }
    #pragma unroll
    for (int rt = 0; rt < 2; rt++)
      #pragma unroll
      for (int ct = 0; ct < 4; ct++)
        #pragma unroll
        for (int reg = 0; reg < 4; reg++)
          sB[rb + rt * 16 + quad * 4 + reg][ct * 16 + l15] = f2bf(ac[rt][ct][reg]);
    __syncthreads();
    #pragma unroll
    for (int v = 0; v < 4; v++) {
      int idx = v * 256 + tid;
      int e = idx >> 3, cg = idx & 7;
      uint4 p = *(const uint4*)&sB[e][cg * 8];
      *(uint4*)&tpw[(size_t)(e0 + e) * 384 + ch * 64 + cg * 8] = p;
    }
    __syncthreads();
  }
}

// ---------------- CSR build ----------------
__global__ void k_hist(const int* __restrict__ recv, int* __restrict__ counts) {
  int e = blockIdx.x * 256 + threadIdx.x;
  if (e < N_EDGES) atomicAdd(&counts[recv[e]], 1);
}

__global__ __launch_bounds__(1024) void k_scan(const int* __restrict__ counts,
                                               int* __restrict__ offsets,
                                               int* __restrict__ cursor) {
  __shared__ int part[1024];
  int tid = threadIdx.x;
  int base = tid * 10;
  int local[10]; int s = 0;
  #pragma unroll
  for (int i = 0; i < 10; i++) {
    int idx = base + i;
    int c = (idx < N_NODES) ? counts[idx] : 0;
    local[i] = s; s += c;
  }
  part[tid] = s;
  __syncthreads();
  for (int off = 1; off < 1024; off <<= 1) {
    int v = (tid >= off) ? part[tid - off] : 0;
    __syncthreads();
    part[tid] += v;
    __syncthreads();
  }
  int pre = (tid > 0) ? part[tid - 1] : 0;
  #pragma unroll
  for (int i = 0; i < 10; i++) {
    int idx = base + i;
    if (idx < N_NODES) { int o = pre + local[i]; offsets[idx] = o; cursor[idx] = o; }
  }
  if (tid == 1023) offsets[N_NODES] = part[1023];
}

__global__ void k_scatter(const int* __restrict__ recv, int* __restrict__ cursor,
                          int* __restrict__ order) {
  int e = blockIdx.x * 256 + threadIdx.x;
  if (e < N_EDGES) {
    int idx = atomicAdd(&cursor[recv[e]], 1);
    order[idx] = e;
  }
}

// ---------------- per-node gather: conv_tp + segment sum -> msg (bf16) ----------
__device__ __forceinline__ void edge_acc(int e, int u,
    const float* __restrict__ h, const unsigned short* __restrict__ tpw,
    const float* __restrict__ yr, const float* __restrict__ yi,
    const int* __restrict__ send, float* mr, float* mi) {
  int s = send[e];
  float xv = h[s * 128 + u];
  __hip_bfloat16 b0 = *(const __hip_bfloat16*)&tpw[e * 384 + u];
  __hip_bfloat16 b1 = *(const __hip_bfloat16*)&tpw[e * 384 + 128 + u];
  __hip_bfloat16 b2 = *(const __hip_bfloat16*)&tpw[e * 384 + 256 + u];
  float xw0 = xv * __bfloat162float(b0);
  float xw1 = xv * __bfloat162float(b1);
  float xw2 = xv * __bfloat162float(b2);
  const float* yre = &yr[e * 9];
  const float* yie = &yi[e * 9];
  mr[0] += xw0 * yre[0]; mi[0] += xw0 * yie[0];
  #pragma unroll
  for (int m = 1; m < 4; m++) { mr[m] += xw1 * yre[m]; mi[m] += xw1 * yie[m]; }
  #pragma unroll
  for (int m = 4; m < 9; m++) { mr[m] += xw2 * yre[m]; mi[m] += xw2 * yie[m]; }
}

__global__ __launch_bounds__(128) void k_gather(
    const float* __restrict__ h, const unsigned short* __restrict__ tpw,
    const float* __restrict__ yr, const float* __restrict__ yi,
    const int* __restrict__ send, const int* __restrict__ offsets,
    const int* __restrict__ order,
    unsigned short* __restrict__ msg) {
  int u = threadIdx.x;
  int n = blockIdx.x;
  float mr[9] = {}, mi[9] = {};
  int e0 = offsets[n], e1 = offsets[n + 1];
  int jj = e0;
  for (; jj + 1 < e1; jj += 2) {
    int ea = order[jj];
    int eb = order[jj + 1];
    edge_acc(ea, u, h, tpw, yr, yi, send, mr, mi);
    edge_acc(eb, u, h, tpw, yr, yi, send, mr, mi);
  }
  if (jj < e1) {
    int ea = order[jj];
    edge_acc(ea, u, h, tpw, yr, yi, send, mr, mi);
  }
  int g = n >> 3, i = n & 7;
  unsigned short* mg = msg + (size_t)g * 144 * 128;
  mg[(i * 2 + 0) * 128 + u] = f2bf(mr[0]);
  mg[(i * 2 + 1) * 128 + u] = f2bf(mi[0]);
  #pragma unroll
  for (int m = 1; m < 4; m++) {
    mg[(16 + i * 6 + (m - 1)) * 128 + u] = f2bf(mr[m]);
    mg[(16 + i * 6 + 3 + (m - 1)) * 128 + u] = f2bf(mi[m]);
  }
  #pragma unroll
  for (int m = 4; m < 9; m++) {
    mg[(64 + i * 10 + (m - 4)) * 128 + u] = f2bf(mr[m]);
    mg[(64 + i * 10 + 5 + (m - 4)) * 128 + u] = f2bf(mi[m]);
  }
}

// ---------------- linear via MFMA ----------------
__global__ __launch_bounds__(256) void k_lin(const unsigned short* __restrict__ msg,
                                             const unsigned short* __restrict__ wlT,
                                             float* __restrict__ out) {
  int tid = threadIdx.x;
  int w = tid >> 6, lane = tid & 63;
  int l15 = lane & 15, quad = lane >> 4;
  int g = blockIdx.x;

  bf16x8 bfr[3][2][4];
  #pragma unroll
  for (int l = 0; l < 3; l++)
    #pragma unroll
    for (int kt = 0; kt < 2; kt++)
      #pragma unroll
      for (int ks = 0; ks < 4; ks++) {
        int ncol = w * 32 + kt * 16 + l15;
        bfr[l][kt][ks] = *(const bf16x8*)&wlT[(l * 128 + ncol) * 128 + ks * 32 + quad * 8];
      }

  const unsigned short* mg = msg + (size_t)g * 144 * 128;

  #pragma unroll
  for (int tile = 0; tile < 9; tile++) {
    const int l = (tile == 0) ? 0 : (tile < 4) ? 1 : 2;
    const int rbase = tile * 16;
    bf16x8 af[4];
    #pragma unroll
    for (int ks = 0; ks < 4; ks++)
      af[ks] = *(const bf16x8*)&mg[(rbase + l15) * 128 + ks * 32 + quad * 8];
    f32x4 acc0 = {}, acc1 = {};
    #pragma unroll
    for (int ks = 0; ks < 4; ks++) {
      acc0 = __builtin_amdgcn_mfma_f32_16x16x32_bf16(af[ks], bfr[l][0][ks], acc0, 0, 0, 0);
      acc1 = __builtin_amdgcn_mfma_f32_16x16x32_bf16(af[ks], bfr[l][1][ks], acc1, 0, 0, 0);
    }
    #pragma unroll
    for (int reg = 0; reg < 4; reg++) {
      int r = rbase + quad * 4 + reg;
      int c, ni, m;
      if (tile == 0) { ni = (r & 15) >> 1; c = r & 1; m = 0; }
      else if (tile < 4) {
        int q = r - 16; ni = q / 6; int rem = q - ni * 6;
        c = rem >= 3; m = 1 + rem - (c ? 3 : 0);
      } else {
        int q = r - 64; ni = q / 10; int rem = q - ni * 10;
        c = rem >= 5; m = 4 + rem - (c ? 5 : 0);
      }
      int node = g * 8 + ni;
      float* ob = out + (size_t)c * 11520000 + node * 1152 + m;
      int k0 = w * 32 + l15;
      ob[(k0)      * 9] = acc0[reg];
      ob[(k0 + 16) * 9] = acc1[reg];
    }
  }
}

// ---------------- launch ----------------
extern "C" void kernel_launch(void* const* d_in, const int* in_sizes, int n_in,
                              void* d_out, int out_size, void* d_ws, size_t ws_size,
                              hipStream_t stream) {
  const float* node_attrs = (const float*)d_in[0];
  const float* node_feats = (const float*)d_in[1];
  const float* ear   = (const float*)d_in[2];
  const float* eai   = (const float*)d_in[3];
  const float* ef    = (const float*)d_in[4];
  const int*   eidx  = (const int*)d_in[5];
  const float* Wup   = (const float*)d_in[6];
  const float* Wskip = (const float*)d_in[7];
  const float* W1    = (const float*)d_in[8];
  const float* W2    = (const float*)d_in[9];
  const float* W3    = (const float*)d_in[10];
  const float* W4    = (const float*)d_in[11];
  const float* Wl0   = (const float*)d_in[12];
  const float* Wl1   = (const float*)d_in[13];
  const float* Wl2   = (const float*)d_in[14];
  float* out = (float*)d_out;

  // workspace layout (bytes):
  char* ws = (char*)d_ws;
  float*          h       = (float*)ws;                              //   5,120,000
  unsigned short* tpw     = (unsigned short*)(ws + 5120000);         //  98,304,000
  unsigned short* msg     = (unsigned short*)(ws + 103424000);       //  46,080,000
  unsigned short* wlT     = (unsigned short*)(ws + 149504000);       //      98,304
  unsigned short* wbT     = (unsigned short*)(ws + 149602304);       //     327,680
  int*            counts  = (int*)(ws + 149929984);
  int*            offsets = (int*)(ws + 149969984);
  int*            cursor  = (int*)(ws + 150010112);
  int*            order   = (int*)(ws + 150050112);                  //     512,000
  unsigned short* w1f     = (unsigned short*)(ws + 150562816);       //       4,096
  unsigned short* w2f     = (unsigned short*)(ws + 150566912);       //       8,192
  unsigned short* w3f     = (unsigned short*)(ws + 150575104);       //       8,192
  unsigned short* w4f     = (unsigned short*)(ws + 150583296);       //      49,152

  const int* send = eidx;
  const int* recv = eidx + N_EDGES;

  hipMemsetAsync(counts, 0, N_NODES * sizeof(int), stream);
  k_hist<<<dim3(500), dim3(256), 0, stream>>>(recv, counts);
  k_scan<<<dim3(1), dim3(1024), 0, stream>>>(counts, offsets, cursor);
  k_scatter<<<dim3(500), dim3(256), 0, stream>>>(recv, cursor, order);
  k_wcvt<<<dim3(832), dim3(256), 0, stream>>>(Wskip, Wl0, Wl1, Wl2, wbT, wlT);
  k_wcvt2<<<dim3(136), dim3(256), 0, stream>>>(W1, W2, W3, W4, w1f, w2f, w3f, w4f);
  k_h<<<dim3(313), dim3(256), 0, stream>>>(node_feats, Wup, h);
  k_sc<<<dim3(313), dim3(256), 0, stream>>>(node_feats, node_attrs, wbT,
                                            out + 2 * 11520000);
  k_mlp<<<dim3(1000), dim3(256), 0, stream>>>(ef, w1f, w2f, w3f, w4f, tpw);
  k_gather<<<dim3(10000), dim3(128), 0, stream>>>(h, tpw, ear, eai, send, offsets,
                                                  order, msg);
  k_lin<<<dim3(1250), dim3(256), 0, stream>>>(msg, wlT, out);
  (void)in_sizes; (void)n_in; (void)out_size; (void)ws_size;
}